// Round 7
// baseline (424.143 us; speedup 1.0000x reference)
//
#include <hip/hip_runtime.h>

#define NT     65536
#define NGRID  28
#define NX     19
#define HDIM   20
#define PF     4
#define CHUNK  512
#define WARM   64
#define NCHUNK (NT / CHUNK)   // 128

typedef float f2 __attribute__((ext_vector_type(2)));
typedef float f4 __attribute__((ext_vector_type(4)));

__device__ __forceinline__ float frcp(float v) { return __builtin_amdgcn_rcpf(v); }

// packed f32 FMA: acc.lo += a.lo*b.lo, acc.hi += a.hi*b.hi
__device__ __forceinline__ void pk_fma(f2& acc, f2 a, f2 b) {
    asm("v_pk_fma_f32 %0, %1, %2, %0" : "+v"(acc) : "v"(a), "v"(b));
}

// 4-lane (quad) sum via DPP quad_perm butterflies — VALU-speed, all lanes get the sum.
// Patterns: [1,0,3,2]=0xB1, [2,3,0,1]=0x4E (rocPRIM's quad-reduce idiom).
__device__ __forceinline__ float quad_sum(float v) {
    float a = v + __builtin_bit_cast(float,
        __builtin_amdgcn_update_dpp(0, __builtin_bit_cast(int, v), 0xB1, 0xF, 0xF, true));
    return a + __builtin_bit_cast(float,
        __builtin_amdgcn_update_dpp(0, __builtin_bit_cast(int, a), 0x4E, 0xF, 0xF, true));
}

// Combined 48-wide weight vector of gate row r, output-feedback absorbed:
// [0..18]=W_ih[r][0..18], [19]=0 (x pad), [20..39]=W_hh[r]+W_ih[r][19]*W_out, [40..47]=0
__device__ __forceinline__ float gw(const float* W_ih, const float* W_hh,
                                    const float* W_out, int r, int k) {
    if (k < NX) return W_ih[r * 20 + k];
    if (k >= 20 && k < 40)
        return fmaf(W_ih[r * 20 + 19], W_out[k - 20], W_hh[r * 20 + (k - 20)]);
    return 0.f;
}

// One wave per (chunk, cell). Lane l owns gate row l (20 f2 weights). The 16
// o-rows 64..79 are quad-shared: quad q computes row 64+q via per-lane 12-wide
// quarters of the combined [x|h|pad] operand (4 distinct LDS addrs -> conflict-
// free) + DPP quad reduction; lane l%4==0 activates & writes. The out row
// (w_out) is computed by every quad from the same operand reads; lane 0 stores
// out_{t-1}. Per-lane weights: 32 f2 -> total VGPR demand ~60, so weights stay
// resident even at a 64-VGPR allocation (round 5/6: 80 f2 -> AGPR round-trips,
// +85 VALU insts/step measured).
__global__ __launch_bounds__(64, 4) void lstm_quad_kernel(
    const float* __restrict__ x,      // (NT, NGRID, NX)
    const float* __restrict__ W_ih,   // (80, 20)
    const float* __restrict__ W_hh,   // (80, 20)
    const float* __restrict__ b_ih,   // (80,)
    const float* __restrict__ b_hh,   // (80,)
    const float* __restrict__ W_out,  // (1, 20)
    const float* __restrict__ b_out,  // (1,)
    float* __restrict__ out)          // (NT, NGRID)
{
    __shared__ __align__(16) float cls[2][48];   // [x_t(20) | h_{t-1}(20) | 0(8)], ping-pong
    __shared__ __align__(16) float gls[20][4];   // activated gates, unit-major (si,sf,tg,so)

    const int b  = blockIdx.x;
    const int ci = b / NGRID;
    const int g  = b - ci * NGRID;
    const int l  = threadIdx.x;
    const int qd = l >> 2;          // quad index 0..15
    const int qi = l & 3;           // lane-in-quad
    const int qb = 12 * qi;         // quarter base in combined vector

    const int tstart = ci * CHUNK;
    const int t0     = (ci == 0) ? 0 : tstart - WARM;

    const int g1 = l / HDIM;        // own row's gate class (0=i,1=f,2=g,3=o)
    const int u1 = l % HDIM;        // own row's unit

    const float bout = b_out[0];

    // ---- own row (row l): 20 f2 over combined k=0..39 ----
    f2 w_own[20];
#pragma unroll
    for (int kk = 0; kk < 20; ++kk)
        w_own[kk] = f2{gw(W_ih, W_hh, W_out, l, 2 * kk),
                       gw(W_ih, W_hh, W_out, l, 2 * kk + 1)};
    const float bb1 = b_ih[l] + b_hh[l];
    const float b1f = fmaf(W_ih[l * 20 + 19], bout, bb1);   // absorbed bias (t>0)
    float b1c = (ci == 0) ? bb1 : b1f;                      // true t=0: prev=0

    // ---- quad-shared o-row rs = 64+qd: this lane's 12-wide quarter ----
    const int rs = 64 + qd;
    f2 w_sh[6];
#pragma unroll
    for (int m = 0; m < 6; ++m)
        w_sh[m] = f2{gw(W_ih, W_hh, W_out, rs, qb + 2 * m),
                     gw(W_ih, W_hh, W_out, rs, qb + 2 * m + 1)};
    const float bbs = b_ih[rs] + b_hh[rs];
    const float bsf = fmaf(W_ih[rs * 20 + 19], bout, bbs);
    float bsc = (ci == 0) ? bbs : bsf;

    // ---- out row quarter: nonzero only in h-part (k 20..39 -> W_out) ----
    f2 w_oq[6];
#pragma unroll
    for (int m = 0; m < 6; ++m) {
        const int k0 = qb + 2 * m, k1 = k0 + 1;
        w_oq[m] = f2{(k0 >= 20 && k0 < 40) ? W_out[k0 - 20] : 0.f,
                     (k1 >= 20 && k1 < 40) ? W_out[k1 - 20] : 0.f};
    }

    // own-row activation: sigmoid (g1!=2) or tanh (g1==2): act = A + B*rcp(1+exp(m*a))
    const float m1 = (g1 == 2) ?  2.f : -1.f;
    const float A1 = (g1 == 2) ?  1.f :  0.f;
    const float B1 = (g1 == 2) ? -2.f :  1.f;

    // ---- x pipeline: lane k<19 holds x[t][g][k]; depth-PF register prefetch ----
    const int    kl   = (l < NX) ? l : 0;
    const float* xptr = x + (size_t)g * NX + kl;
    const size_t tsx  = (size_t)NGRID * NX;
    float xr[PF];
#pragma unroll
    for (int p = 0; p < PF; ++p) {
        int tp = t0 + 1 + p; if (tp > NT - 1) tp = NT - 1;
        xr[p] = xptr[(size_t)tp * tsx];
    }
    // prime LDS: pads, h_{t0-1}=0, x_{t0}
    if (l < 8)    { cls[0][40 + l] = 0.f; cls[1][40 + l] = 0.f; }
    if (l < HDIM) { cls[0][20 + l] = 0.f; cls[0][l] = xptr[(size_t)t0 * tsx]; }

    float  c  = 0.f;
    int    px = 0;
    float* op = out + (size_t)tstart * NGRID + g;

#define STEP(T, DO_STORE)                                                      \
    {                                                                          \
        if (l < HDIM) cls[px ^ 1][l] = xr[0];        /* stage x_{T+1} */       \
        int tf_ = (T) + 1 + PF; if (tf_ > NT - 1) tf_ = NT - 1;                \
        const float xf_ = xptr[(size_t)tf_ * tsx];                             \
        /* own row: 10 broadcast b128 reads, 20 pk_fma (2 chains) */           \
        f2 aA = f2{b1c, 0.f}, aB = f2{0.f, 0.f};                               \
        _Pragma("unroll")                                                      \
        for (int ii = 0; ii < 10; ++ii) {                                      \
            const f4 X = ((const f4*)&cls[px][0])[ii];                         \
            pk_fma(aA, f2{X.x, X.y}, w_own[2 * ii]);                           \
            pk_fma(aB, f2{X.z, X.w}, w_own[2 * ii + 1]);                       \
        }                                                                      \
        /* quarter operands (4 distinct addrs/wave, conflict-free) */          \
        const f4 Q0 = *(const f4*)&cls[px][qb];                                \
        const f4 Q1 = *(const f4*)&cls[px][qb + 4];                            \
        const f4 Q2 = *(const f4*)&cls[px][qb + 8];                            \
        f2 sS = f2{0.f, 0.f}, sO = f2{0.f, 0.f};                               \
        pk_fma(sS, f2{Q0.x, Q0.y}, w_sh[0]); pk_fma(sO, f2{Q0.x, Q0.y}, w_oq[0]); \
        pk_fma(sS, f2{Q0.z, Q0.w}, w_sh[1]); pk_fma(sO, f2{Q0.z, Q0.w}, w_oq[1]); \
        pk_fma(sS, f2{Q1.x, Q1.y}, w_sh[2]); pk_fma(sO, f2{Q1.x, Q1.y}, w_oq[2]); \
        pk_fma(sS, f2{Q1.z, Q1.w}, w_sh[3]); pk_fma(sO, f2{Q1.z, Q1.w}, w_oq[3]); \
        pk_fma(sS, f2{Q2.x, Q2.y}, w_sh[4]); pk_fma(sO, f2{Q2.x, Q2.y}, w_oq[4]); \
        pk_fma(sS, f2{Q2.z, Q2.w}, w_sh[5]); pk_fma(sO, f2{Q2.z, Q2.w}, w_oq[5]); \
        const float vs = quad_sum(sS.x + sS.y);      /* shared o-row preact */ \
        const float vo = quad_sum(sO.x + sO.y);      /* out_{T-1} - bout   */  \
        /* own activation -> gls[unit][gate] */                                \
        const float a1 = aA.x + aA.y + aB.x + aB.y;                            \
        const float e1 = __expf(m1 * a1);                                      \
        gls[u1][g1] = fmaf(B1, frcp(1.f + e1), A1);                            \
        /* shared o activation (quad writer) */                                \
        if (qi == 0) gls[4 + qd][3] = frcp(1.f + __expf(-(vs + bsc)));         \
        if (DO_STORE) { if (l == 0) *op = vo + bout; op += NGRID; }            \
        /* state update on unit owners; h_T -> next buffer */                  \
        if (l < HDIM) {                                                        \
            const f4 gv = *(const f4*)&gls[l][0];    /* si, sf, tg, so */      \
            c = fmaf(gv.y, c, gv.x * gv.z);                                    \
            const float ec = __expf(2.f * c);                                  \
            cls[px ^ 1][20 + l] = gv.w * (1.f - 2.f * frcp(1.f + ec));         \
        }                                                                      \
        _Pragma("unroll")                                                      \
        for (int i_ = 0; i_ < PF - 1; ++i_) xr[i_] = xr[i_ + 1];               \
        xr[PF - 1] = xf_;                                                      \
        px ^= 1;                                                               \
    }

    // peeled first step (unabsorbed bias for chunk 0), then warm, then main
    STEP(t0, false);
    b1c = b1f; bsc = bsf;
    for (int t = t0 + 1; t <= tstart; ++t) STEP(t, false);
    for (int t = tstart + 1; t <= tstart + CHUNK; ++t) STEP(t, true);
#undef STEP
}

extern "C" void kernel_launch(void* const* d_in, const int* in_sizes, int n_in,
                              void* d_out, int out_size, void* d_ws, size_t ws_size,
                              hipStream_t stream) {
    const float* x     = (const float*)d_in[0];
    const float* W_ih  = (const float*)d_in[1];
    const float* W_hh  = (const float*)d_in[2];
    const float* b_ih  = (const float*)d_in[3];
    const float* b_hh  = (const float*)d_in[4];
    const float* W_out = (const float*)d_in[5];
    const float* b_out = (const float*)d_in[6];
    float* out = (float*)d_out;

    lstm_quad_kernel<<<dim3(NCHUNK * NGRID), dim3(64), 0, stream>>>(
        x, W_ih, W_hh, b_ih, b_hh, W_out, b_out, out);
}

// Round 8
// 412.339 us; speedup vs baseline: 1.0286x; 1.0286x over previous
//
#include <hip/hip_runtime.h>

#define NT     65536
#define NGRID  28
#define NX     19
#define HDIM   20
#define PF     4
#define CHUNK  512
#define WARM   64
#define NCHUNK (NT / CHUNK)   // 128

typedef float f2 __attribute__((ext_vector_type(2)));
typedef float f4 __attribute__((ext_vector_type(4)));

__device__ __forceinline__ float frcp(float v) { return __builtin_amdgcn_rcpf(v); }

// packed f32 FMA: acc.lo += a.lo*b.lo, acc.hi += a.hi*b.hi
__device__ __forceinline__ void pk_fma(f2& acc, f2 a, f2 b) {
    asm("v_pk_fma_f32 %0, %1, %2, %0" : "+v"(acc) : "v"(a), "v"(b));
}

// 4-lane (quad) sum via DPP quad_perm butterflies — VALU-speed, all lanes get the sum.
// Patterns: [1,0,3,2]=0xB1, [2,3,0,1]=0x4E (rocPRIM's quad-reduce idiom).
__device__ __forceinline__ float quad_sum(float v) {
    float a = v + __builtin_bit_cast(float,
        __builtin_amdgcn_update_dpp(0, __builtin_bit_cast(int, v), 0xB1, 0xF, 0xF, true));
    return a + __builtin_bit_cast(float,
        __builtin_amdgcn_update_dpp(0, __builtin_bit_cast(int, a), 0x4E, 0xF, 0xF, true));
}

// Combined 48-wide weight vector of gate row r, output-feedback absorbed:
// [0..18]=W_ih[r][0..18], [19]=0 (x pad), [20..39]=W_hh[r]+W_ih[r][19]*W_out, [40..47]=0
__device__ __forceinline__ float gw(const float* W_ih, const float* W_hh,
                                    const float* W_out, int r, int k) {
    if (k < NX) return W_ih[r * 20 + k];
    if (k >= 20 && k < 40)
        return fmaf(W_ih[r * 20 + 19], W_out[k - 20], W_hh[r * 20 + (k - 20)]);
    return 0.f;
}

// One wave per (chunk, cell). Lane l owns gate row l (20 f2 weights). The 16
// o-rows 64..79 are quad-shared: quad q computes row 64+q via per-lane 12-wide
// quarters of the combined [x|h|pad] operand (4 distinct LDS addrs -> conflict-
// free) + DPP quad reduction; lane l%4==0 activates & writes. The out row
// (w_out) is computed by every quad from the same operand reads; lane 0 stores
// out_{t-1}.
//
// __launch_bounds__(64, 2): rounds 5-7 showed the allocator pinning arch VGPRs
// at 64 and parking the ~64 VGPRs of packed weights in AGPRs (unified file) —
// every weight use then costs a v_accvgpr_read, measured as ~160 VALU
// insts/step vs ~85 in source. A 256-reg budget (min 2 waves/EU) lets the
// weights live in arch VGPRs; demand ~95 stays in the 65-128 granule, so
// residency (4 waves/SIMD) still covers the grid's 3.5 waves/SIMD.
__global__ __launch_bounds__(64, 2) void lstm_quad_kernel(
    const float* __restrict__ x,      // (NT, NGRID, NX)
    const float* __restrict__ W_ih,   // (80, 20)
    const float* __restrict__ W_hh,   // (80, 20)
    const float* __restrict__ b_ih,   // (80,)
    const float* __restrict__ b_hh,   // (80,)
    const float* __restrict__ W_out,  // (1, 20)
    const float* __restrict__ b_out,  // (1,)
    float* __restrict__ out)          // (NT, NGRID)
{
    __shared__ __align__(16) float cls[2][48];   // [x_t(20) | h_{t-1}(20) | 0(8)], ping-pong
    __shared__ __align__(16) float gls[20][4];   // activated gates, unit-major (si,sf,tg,so)

    const int b  = blockIdx.x;
    const int ci = b / NGRID;
    const int g  = b - ci * NGRID;
    const int l  = threadIdx.x;
    const int qd = l >> 2;          // quad index 0..15
    const int qi = l & 3;           // lane-in-quad
    const int qb = 12 * qi;         // quarter base in combined vector

    const int tstart = ci * CHUNK;
    const int t0     = (ci == 0) ? 0 : tstart - WARM;

    const int g1 = l / HDIM;        // own row's gate class (0=i,1=f,2=g,3=o)
    const int u1 = l % HDIM;        // own row's unit

    const float bout = b_out[0];

    // ---- own row (row l): 20 f2 over combined k=0..39 ----
    f2 w_own[20];
#pragma unroll
    for (int kk = 0; kk < 20; ++kk)
        w_own[kk] = f2{gw(W_ih, W_hh, W_out, l, 2 * kk),
                       gw(W_ih, W_hh, W_out, l, 2 * kk + 1)};
    const float bb1 = b_ih[l] + b_hh[l];
    const float b1f = fmaf(W_ih[l * 20 + 19], bout, bb1);   // absorbed bias (t>0)
    float b1c = (ci == 0) ? bb1 : b1f;                      // true t=0: prev=0

    // ---- quad-shared o-row rs = 64+qd: this lane's 12-wide quarter ----
    const int rs = 64 + qd;
    f2 w_sh[6];
#pragma unroll
    for (int m = 0; m < 6; ++m)
        w_sh[m] = f2{gw(W_ih, W_hh, W_out, rs, qb + 2 * m),
                     gw(W_ih, W_hh, W_out, rs, qb + 2 * m + 1)};
    const float bbs = b_ih[rs] + b_hh[rs];
    const float bsf = fmaf(W_ih[rs * 20 + 19], bout, bbs);
    float bsc = (ci == 0) ? bbs : bsf;

    // ---- out row quarter: nonzero only in h-part (k 20..39 -> W_out) ----
    f2 w_oq[6];
#pragma unroll
    for (int m = 0; m < 6; ++m) {
        const int k0 = qb + 2 * m, k1 = k0 + 1;
        w_oq[m] = f2{(k0 >= 20 && k0 < 40) ? W_out[k0 - 20] : 0.f,
                     (k1 >= 20 && k1 < 40) ? W_out[k1 - 20] : 0.f};
    }

    // own-row activation: sigmoid (g1!=2) or tanh (g1==2): act = A + B*rcp(1+exp(m*a))
    const float m1 = (g1 == 2) ?  2.f : -1.f;
    const float A1 = (g1 == 2) ?  1.f :  0.f;
    const float B1 = (g1 == 2) ? -2.f :  1.f;

    // ---- x pipeline: lane k<19 holds x[t][g][k]; depth-PF register prefetch ----
    const int    kl   = (l < NX) ? l : 0;
    const float* xptr = x + (size_t)g * NX + kl;
    const size_t tsx  = (size_t)NGRID * NX;
    float xr[PF];
#pragma unroll
    for (int p = 0; p < PF; ++p) {
        int tp = t0 + 1 + p; if (tp > NT - 1) tp = NT - 1;
        xr[p] = xptr[(size_t)tp * tsx];
    }
    // prime LDS: pads, h_{t0-1}=0, x_{t0}
    if (l < 8)    { cls[0][40 + l] = 0.f; cls[1][40 + l] = 0.f; }
    if (l < HDIM) { cls[0][20 + l] = 0.f; cls[0][l] = xptr[(size_t)t0 * tsx]; }

    float  c  = 0.f;
    int    px = 0;
    float* op = out + (size_t)tstart * NGRID + g;

#define STEP(T, DO_STORE)                                                      \
    {                                                                          \
        if (l < HDIM) cls[px ^ 1][l] = xr[0];        /* stage x_{T+1} */       \
        int tf_ = (T) + 1 + PF; if (tf_ > NT - 1) tf_ = NT - 1;                \
        const float xf_ = xptr[(size_t)tf_ * tsx];                             \
        /* own row: 10 broadcast b128 reads, 20 pk_fma (2 chains) */           \
        f2 aA = f2{b1c, 0.f}, aB = f2{0.f, 0.f};                               \
        _Pragma("unroll")                                                      \
        for (int ii = 0; ii < 10; ++ii) {                                      \
            const f4 X = ((const f4*)&cls[px][0])[ii];                         \
            pk_fma(aA, f2{X.x, X.y}, w_own[2 * ii]);                           \
            pk_fma(aB, f2{X.z, X.w}, w_own[2 * ii + 1]);                       \
        }                                                                      \
        /* quarter operands (4 distinct addrs/wave, conflict-free) */          \
        const f4 Q0 = *(const f4*)&cls[px][qb];                                \
        const f4 Q1 = *(const f4*)&cls[px][qb + 4];                            \
        const f4 Q2 = *(const f4*)&cls[px][qb + 8];                            \
        f2 sS = f2{0.f, 0.f}, sO = f2{0.f, 0.f};                               \
        pk_fma(sS, f2{Q0.x, Q0.y}, w_sh[0]); pk_fma(sO, f2{Q0.x, Q0.y}, w_oq[0]); \
        pk_fma(sS, f2{Q0.z, Q0.w}, w_sh[1]); pk_fma(sO, f2{Q0.z, Q0.w}, w_oq[1]); \
        pk_fma(sS, f2{Q1.x, Q1.y}, w_sh[2]); pk_fma(sO, f2{Q1.x, Q1.y}, w_oq[2]); \
        pk_fma(sS, f2{Q1.z, Q1.w}, w_sh[3]); pk_fma(sO, f2{Q1.z, Q1.w}, w_oq[3]); \
        pk_fma(sS, f2{Q2.x, Q2.y}, w_sh[4]); pk_fma(sO, f2{Q2.x, Q2.y}, w_oq[4]); \
        pk_fma(sS, f2{Q2.z, Q2.w}, w_sh[5]); pk_fma(sO, f2{Q2.z, Q2.w}, w_oq[5]); \
        const float vs = quad_sum(sS.x + sS.y);      /* shared o-row preact */ \
        const float vo = quad_sum(sO.x + sO.y);      /* out_{T-1} - bout   */  \
        /* own activation -> gls[unit][gate] */                                \
        const float a1 = aA.x + aA.y + aB.x + aB.y;                            \
        const float e1 = __expf(m1 * a1);                                      \
        gls[u1][g1] = fmaf(B1, frcp(1.f + e1), A1);                            \
        /* shared o activation (quad writer) */                                \
        if (qi == 0) gls[4 + qd][3] = frcp(1.f + __expf(-(vs + bsc)));         \
        if (DO_STORE) { if (l == 0) *op = vo + bout; op += NGRID; }            \
        /* state update on unit owners; h_T -> next buffer */                  \
        asm volatile("s_waitcnt lgkmcnt(0)" ::: "memory");                     \
        if (l < HDIM) {                                                        \
            const f4 gv = *(const f4*)&gls[l][0];    /* si, sf, tg, so */      \
            c = fmaf(gv.y, c, gv.x * gv.z);                                    \
            const float ec = __expf(2.f * c);                                  \
            cls[px ^ 1][20 + l] = gv.w * (1.f - 2.f * frcp(1.f + ec));         \
        }                                                                      \
        _Pragma("unroll")                                                      \
        for (int i_ = 0; i_ < PF - 1; ++i_) xr[i_] = xr[i_ + 1];               \
        xr[PF - 1] = xf_;                                                      \
        px ^= 1;                                                               \
    }

    // peeled first step (unabsorbed bias for chunk 0), then warm, then main
    STEP(t0, false);
    b1c = b1f; bsc = bsf;
    for (int t = t0 + 1; t <= tstart; ++t) STEP(t, false);
    for (int t = tstart + 1; t <= tstart + CHUNK; ++t) STEP(t, true);
#undef STEP
}

extern "C" void kernel_launch(void* const* d_in, const int* in_sizes, int n_in,
                              void* d_out, int out_size, void* d_ws, size_t ws_size,
                              hipStream_t stream) {
    const float* x     = (const float*)d_in[0];
    const float* W_ih  = (const float*)d_in[1];
    const float* W_hh  = (const float*)d_in[2];
    const float* b_ih  = (const float*)d_in[3];
    const float* b_hh  = (const float*)d_in[4];
    const float* W_out = (const float*)d_in[5];
    const float* b_out = (const float*)d_in[6];
    float* out = (float*)d_out;

    lstm_quad_kernel<<<dim3(NCHUNK * NGRID), dim3(64), 0, stream>>>(
        x, W_ih, W_hh, b_ih, b_hh, W_out, b_out, out);
}

// Round 9
// 401.393 us; speedup vs baseline: 1.0567x; 1.0273x over previous
//
#include <hip/hip_runtime.h>

#define NT     65536
#define NGRID  28
#define NX     19
#define HDIM   20
#define PF     4
#define CHUNK  256
#define WARM   64
#define NCHUNK (NT / CHUNK)   // 256

typedef float f2 __attribute__((ext_vector_type(2)));
typedef float f4 __attribute__((ext_vector_type(4)));

#if __has_builtin(__builtin_amdgcn_exp2f)
#define EXP2(x) __builtin_amdgcn_exp2f(x)
#else
#define EXP2(x) exp2f(x)
#endif
#define L2E 1.4426950408889634f

__device__ __forceinline__ float frcp(float v) { return __builtin_amdgcn_rcpf(v); }

// packed f32 FMA: acc.lo += a.lo*b.lo, acc.hi += a.hi*b.hi
__device__ __forceinline__ void pk_fma(f2& acc, f2 a, f2 b) {
    asm("v_pk_fma_f32 %0, %1, %2, %0" : "+v"(acc) : "v"(a), "v"(b));
}

// 4-lane (quad) sum via DPP quad_perm butterflies — all lanes get the sum.
__device__ __forceinline__ float quad_sum(float v) {
    float a = v + __builtin_bit_cast(float,
        __builtin_amdgcn_update_dpp(0, __builtin_bit_cast(int, v), 0xB1, 0xF, 0xF, true));
    return a + __builtin_bit_cast(float,
        __builtin_amdgcn_update_dpp(0, __builtin_bit_cast(int, a), 0x4E, 0xF, 0xF, true));
}

// Combined 48-wide weight vector of gate row r, output-feedback absorbed:
// [0..18]=W_ih[r][0..18], [19]=0 (x pad), [20..39]=W_hh[r]+W_ih[r][19]*W_out, [40..47]=0
__device__ __forceinline__ float gw(const float* W_ih, const float* W_hh,
                                    const float* W_out, int r, int k) {
    if (k < NX) return W_ih[r * 20 + k];
    if (k >= 20 && k < 40)
        return fmaf(W_ih[r * 20 + 19], W_out[k - 20], W_hh[r * 20 + (k - 20)]);
    return 0.f;
}

// One wave per (chunk, cell); structure as round 7/8 (lane l owns gate row l;
// o-rows 64..79 quad-shared over 12-wide quarters + DPP reduce; out row
// computed by every quad from the same operand reads; lane 0 stores out_{t-1}).
// Round 9: CHUNK 256 -> 7168 waves = 7/SIMD launched (was 3.5) to fill the
// 35% VALU-idle measured at round 8; unroll-2 makes ping-pong parity static;
// exp2-direct activations (pre-scaled by log2(e)).
__global__ __launch_bounds__(64, 2) void lstm_quad_kernel(
    const float* __restrict__ x,      // (NT, NGRID, NX)
    const float* __restrict__ W_ih,   // (80, 20)
    const float* __restrict__ W_hh,   // (80, 20)
    const float* __restrict__ b_ih,   // (80,)
    const float* __restrict__ b_hh,   // (80,)
    const float* __restrict__ W_out,  // (1, 20)
    const float* __restrict__ b_out,  // (1,)
    float* __restrict__ out)          // (NT, NGRID)
{
    __shared__ __align__(16) float cls[2][48];   // [x_t(20) | h_{t-1}(20) | 0(8)], ping-pong
    __shared__ __align__(16) float gls[20][4];   // activated gates, unit-major (si,sf,tg,so)

    const int b  = blockIdx.x;
    const int ci = b / NGRID;
    const int g  = b - ci * NGRID;
    const int l  = threadIdx.x;
    const int qd = l >> 2;          // quad index 0..15
    const int qi = l & 3;           // lane-in-quad
    const int qb = 12 * qi;         // quarter base in combined vector

    const int tstart = ci * CHUNK;
    const int t0     = (ci == 0) ? 0 : tstart - WARM;

    const int g1 = l / HDIM;        // own row's gate class (0=i,1=f,2=g,3=o)
    const int u1 = l % HDIM;        // own row's unit

    const float bout = b_out[0];

    // ---- own row (row l): 20 f2 over combined k=0..39 ----
    f2 w_own[20];
#pragma unroll
    for (int kk = 0; kk < 20; ++kk)
        w_own[kk] = f2{gw(W_ih, W_hh, W_out, l, 2 * kk),
                       gw(W_ih, W_hh, W_out, l, 2 * kk + 1)};
    const float bb1 = b_ih[l] + b_hh[l];
    const float b1f = fmaf(W_ih[l * 20 + 19], bout, bb1);   // absorbed bias (t>0)
    float b1c = (ci == 0) ? bb1 : b1f;                      // true t=0: prev=0

    // ---- quad-shared o-row rs = 64+qd: this lane's 12-wide quarter ----
    const int rs = 64 + qd;
    f2 w_sh[6];
#pragma unroll
    for (int m = 0; m < 6; ++m)
        w_sh[m] = f2{gw(W_ih, W_hh, W_out, rs, qb + 2 * m),
                     gw(W_ih, W_hh, W_out, rs, qb + 2 * m + 1)};
    const float bbs = b_ih[rs] + b_hh[rs];
    const float bsf = fmaf(W_ih[rs * 20 + 19], bout, bbs);
    float bsc = (ci == 0) ? bbs : bsf;

    // ---- out row quarter: nonzero only in h-part (k 20..39 -> W_out) ----
    f2 w_oq[6];
#pragma unroll
    for (int m = 0; m < 6; ++m) {
        const int k0 = qb + 2 * m, k1 = k0 + 1;
        w_oq[m] = f2{(k0 >= 20 && k0 < 40) ? W_out[k0 - 20] : 0.f,
                     (k1 >= 20 && k1 < 40) ? W_out[k1 - 20] : 0.f};
    }

    // own-row activation (exp2 form): act = A1 + B1 * rcp(1 + exp2(m1*a))
    // sigmoid (g1!=2): m1 = -log2e; tanh (g1==2): m1 = 2*log2e, A=1, B=-2
    const float m1 = (g1 == 2) ? (2.f * L2E) : -L2E;
    const float A1 = (g1 == 2) ?  1.f :  0.f;
    const float B1 = (g1 == 2) ? -2.f :  1.f;

    // ---- x pipeline: lane k<19 holds x[t][g][k]; depth-PF register prefetch ----
    const int    kl   = (l < NX) ? l : 0;
    const float* xptr = x + (size_t)g * NX + kl;
    const size_t tsx  = (size_t)NGRID * NX;
    float xr[PF];
#pragma unroll
    for (int p = 0; p < PF; ++p) {
        int tp = t0 + 1 + p; if (tp > NT - 1) tp = NT - 1;
        xr[p] = xptr[(size_t)tp * tsx];
    }
    // prime LDS: pads, h_{t0-1}=0, x_{t0}
    if (l < 8)    { cls[0][40 + l] = 0.f; cls[1][40 + l] = 0.f; }
    if (l < HDIM) { cls[0][20 + l] = 0.f; cls[0][l] = xptr[(size_t)t0 * tsx]; }

    float  c  = 0.f;
    int    px = 0;
    float* op = out + (size_t)tstart * NGRID + g;

#define STEP(T, DO_STORE)                                                      \
    {                                                                          \
        if (l < HDIM) cls[px ^ 1][l] = xr[0];        /* stage x_{T+1} */       \
        int tf_ = (T) + 1 + PF; if (tf_ > NT - 1) tf_ = NT - 1;                \
        const float xf_ = xptr[(size_t)tf_ * tsx];                             \
        /* own row: 10 broadcast b128 reads, 20 pk_fma (2 chains) */           \
        f2 aA = f2{b1c, 0.f}, aB = f2{0.f, 0.f};                               \
        _Pragma("unroll")                                                      \
        for (int ii = 0; ii < 10; ++ii) {                                      \
            const f4 X = ((const f4*)&cls[px][0])[ii];                         \
            pk_fma(aA, f2{X.x, X.y}, w_own[2 * ii]);                           \
            pk_fma(aB, f2{X.z, X.w}, w_own[2 * ii + 1]);                       \
        }                                                                      \
        /* quarter operands (4 distinct addrs/wave, conflict-free) */          \
        const f4 Q0 = *(const f4*)&cls[px][qb];                                \
        const f4 Q1 = *(const f4*)&cls[px][qb + 4];                            \
        const f4 Q2 = *(const f4*)&cls[px][qb + 8];                            \
        f2 sS = f2{0.f, 0.f}, sO = f2{0.f, 0.f};                               \
        pk_fma(sS, f2{Q0.x, Q0.y}, w_sh[0]); pk_fma(sO, f2{Q0.x, Q0.y}, w_oq[0]); \
        pk_fma(sS, f2{Q0.z, Q0.w}, w_sh[1]); pk_fma(sO, f2{Q0.z, Q0.w}, w_oq[1]); \
        pk_fma(sS, f2{Q1.x, Q1.y}, w_sh[2]); pk_fma(sO, f2{Q1.x, Q1.y}, w_oq[2]); \
        pk_fma(sS, f2{Q1.z, Q1.w}, w_sh[3]); pk_fma(sO, f2{Q1.z, Q1.w}, w_oq[3]); \
        pk_fma(sS, f2{Q2.x, Q2.y}, w_sh[4]); pk_fma(sO, f2{Q2.x, Q2.y}, w_oq[4]); \
        pk_fma(sS, f2{Q2.z, Q2.w}, w_sh[5]); pk_fma(sO, f2{Q2.z, Q2.w}, w_oq[5]); \
        const float vs = quad_sum(sS.x + sS.y);      /* shared o-row preact */ \
        const float vo = quad_sum(sO.x + sO.y);      /* out_{T-1} - bout   */  \
        /* own activation -> gls[unit][gate] */                                \
        const float a1 = aA.x + aA.y + aB.x + aB.y;                            \
        const float e1 = EXP2(m1 * a1);                                        \
        gls[u1][g1] = fmaf(B1, frcp(1.f + e1), A1);                            \
        /* shared o activation (quad writer) */                                \
        if (qi == 0) gls[4 + qd][3] = frcp(1.f + EXP2(-L2E * (vs + bsc)));     \
        if (DO_STORE) { if (l == 0) *op = vo + bout; op += NGRID; }            \
        /* state update on unit owners; h_T -> next buffer */                  \
        asm volatile("s_waitcnt lgkmcnt(0)" ::: "memory");                     \
        if (l < HDIM) {                                                        \
            const f4 gv = *(const f4*)&gls[l][0];    /* si, sf, tg, so */      \
            c = fmaf(gv.y, c, gv.x * gv.z);                                    \
            const float ec = EXP2(2.f * L2E * c);                              \
            cls[px ^ 1][20 + l] = gv.w * (1.f - 2.f * frcp(1.f + ec));         \
        }                                                                      \
        _Pragma("unroll")                                                      \
        for (int i_ = 0; i_ < PF - 1; ++i_) xr[i_] = xr[i_ + 1];               \
        xr[PF - 1] = xf_;                                                      \
        px ^= 1;                                                               \
    }

    // peeled first step (unabsorbed bias for chunk 0), then warm, then main.
    // unroll 2: px parity becomes compile-time (warm=64, main=256, both even).
    STEP(t0, false);
    b1c = b1f; bsc = bsf;
#pragma unroll 2
    for (int t = t0 + 1; t <= tstart; ++t) STEP(t, false);
#pragma unroll 2
    for (int t = tstart + 1; t <= tstart + CHUNK; ++t) STEP(t, true);
#undef STEP
}

extern "C" void kernel_launch(void* const* d_in, const int* in_sizes, int n_in,
                              void* d_out, int out_size, void* d_ws, size_t ws_size,
                              hipStream_t stream) {
    const float* x     = (const float*)d_in[0];
    const float* W_ih  = (const float*)d_in[1];
    const float* W_hh  = (const float*)d_in[2];
    const float* b_ih  = (const float*)d_in[3];
    const float* b_hh  = (const float*)d_in[4];
    const float* W_out = (const float*)d_in[5];
    const float* b_out = (const float*)d_in[6];
    float* out = (float*)d_out;

    lstm_quad_kernel<<<dim3(NCHUNK * NGRID), dim3(64), 0, stream>>>(
        x, W_ih, W_hh, b_ih, b_hh, W_out, b_out, out);
}